// Round 3
// baseline (242.217 us; speedup 1.0000x reference)
//
#include <hip/hip_runtime.h>

#define HH 512
#define WW 512
#define BATCH 32
#define BH 16                 // output rows per block
#define NB (HH / BH)          // 32
#define TPB 256               // 4 waves; 2 cols/thread -> full 512-col coverage
#define NBLOCKS (NB * BATCH)  // 1024
#define CBASE 0xAAAAAAAAu     // harness poisons d_ws to 0xAA before every launch

// R14: ZERO-LDS / ZERO-BARRIER register streaming. Evidence: R11 (best, ~55us
// dispatch) has all pipes idle >=60% (VALU 30%, LDS ~41% modeled, HBM 12%);
// R12 (more blocks) and R13 (intra-phase ILP) both failed -> the barrier-phased
// vert->LDS->horiz structure is the wall (16 barriers/block, lock-step convoy).
// New structure: horizontal blur FIRST from a per-thread 16-col register
// window (redundant loads, L1-served), then vertical blur in registers via an
// 11-row ring of h-values (5 arrays x 11 x f2 = 110 VGPR). 26-row loop fully
// unrolled -> all ring indices static (no scratch). No __syncthreads in the
// main loop; threads fully independent.
// Predicted: VALUBusy 30->55-75%, LDS_BANK_CONFLICT ~0, dur 55 -> 28-38us.
// Tripwires: WRITE_SIZE ~68KB (ring spill if >>), VGPR<=256. If VALUBusy
// stays <=40% with dur >=45us: load-latency-bound -> add prefetch next.

typedef float f2 __attribute__((ext_vector_type(2)));

__global__ __launch_bounds__(TPB) void ssim_main(
    const float* __restrict__ img1,
    const float* __restrict__ img2,
    unsigned* __restrict__ counter,     // ws + 0   (starts at CBASE, poisoned)
    float* __restrict__ partial,        // ws + 16  (NBLOCKS floats)
    float* __restrict__ out)
{
  constexpr float G[11] = {
      0.00102838f, 0.00759876f, 0.03600077f, 0.10936070f, 0.21300553f,
      0.26601171f,
      0.21300553f, 0.10936070f, 0.03600077f, 0.00759876f, 0.00102838f};
  constexpr float C1 = 1.0e-4f;
  constexpr float C2 = 9.0e-4f;

  const int tid  = threadIdx.x;
  const int band = blockIdx.x;
  const int bat  = blockIdx.y;
  const int r0   = band * BH;
  const float* p1 = img1 + (size_t)bat * (HH * WW);
  const float* p2 = img2 + (size_t)bat * (HH * WW);
  const int c0 = tid * 2;
  const int s0 = c0 - 6;                     // 16-col window s0..s0+15 (8B aligned)
  const bool fast = (c0 >= 6) && (c0 <= 502);  // window fully in [0,512)

  // Ring of horizontally-blurred rows: hw[slot][array], f2 over (c0, c0+1).
  // slot = row_index % 11, statically resolved by full unroll.
  f2 hw[11][5];

  float ssum = 0.f;

#pragma unroll
  for (int rr = 0; rr < BH + 10; ++rr) {     // input rows r0-5 .. r0+BH+4
    const int r = r0 - 5 + rr;
    f2 ha = f2{0.f, 0.f}, hb = ha, hc = ha, hd = ha, he = ha;

    if (r >= 0 && r < HH) {                  // block-uniform branch
      float w1[16], w2[16];
      if (fast) {
        const float* a1 = p1 + r * WW + s0;
        const float* a2 = p2 + r * WW + s0;
#pragma unroll
        for (int m = 0; m < 8; ++m) {        // aligned f2 loads; unused pairs DCE'd
          *(f2*)(w1 + 2 * m) = *(const f2*)(a1 + 2 * m);
          *(f2*)(w2 + 2 * m) = *(const f2*)(a2 + 2 * m);
        }
      } else {
#pragma unroll
        for (int j = 0; j < 16; ++j) { w1[j] = 0.f; w2[j] = 0.f; }
#pragma unroll
        for (int j = 1; j <= 12; ++j) {      // only w[1..12] are consumed
          const int col = s0 + j;
          if (col >= 0 && col < WW) {
            w1[j] = p1[r * WW + col];
            w2[j] = p2[r * WW + col];
          }
        }
      }
      // Horizontal 11-tap blur of x, y, xx, yy, xy for output cols (c0, c0+1).
      // Tap k touches cols (c0-5+k, c0-4+k) = window indices (k+1, k+2).
#pragma unroll
      for (int k = 0; k < 11; ++k) {
        const f2 g2 = f2{G[k], G[k]};
        const f2 x = f2{w1[k + 1], w1[k + 2]};
        const f2 y = f2{w2[k + 1], w2[k + 2]};
        ha = __builtin_elementwise_fma(g2, x, ha);
        hb = __builtin_elementwise_fma(g2, y, hb);
        hc = __builtin_elementwise_fma(g2, x * x, hc);
        hd = __builtin_elementwise_fma(g2, y * y, hd);
        he = __builtin_elementwise_fma(g2, x * y, he);
      }
    }

    {
      const int sl = rr % 11;                // static after unroll
      hw[sl][0] = ha; hw[sl][1] = hb; hw[sl][2] = hc;
      hw[sl][3] = hd; hw[sl][4] = he;
    }

    if (rr >= 10) {
      // Output row ro = r0 + rr - 10 uses input rows rr-10 .. rr (weights G[0..10]).
      f2 m1 = f2{0.f, 0.f}, m2 = m1, sxx = m1, syy = m1, sxy = m1;
#pragma unroll
      for (int d = 0; d < 11; ++d) {
        const int s = (rr - 10 + d) % 11;    // static after unroll
        const f2 g2 = f2{G[d], G[d]};
        m1  = __builtin_elementwise_fma(g2, hw[s][0], m1);
        m2  = __builtin_elementwise_fma(g2, hw[s][1], m2);
        sxx = __builtin_elementwise_fma(g2, hw[s][2], sxx);
        syy = __builtin_elementwise_fma(g2, hw[s][3], syy);
        sxy = __builtin_elementwise_fma(g2, hw[s][4], sxy);
      }
      // SSIM map (identical numerics to R11)
      const f2 mu12 = m1 * m2;
      const f2 den1 = __builtin_elementwise_fma(
          m1, m1, __builtin_elementwise_fma(m2, m2, f2{C1, C1}));
      const f2 vs   = (sxx + syy) - den1 + f2{C1 + C2, C1 + C2};
      const f2 sg12 = sxy - mu12;
      const f2 num = (mu12 + mu12 + f2{C1, C1}) * (sg12 + sg12 + f2{C2, C2});
      const f2 den = den1 * vs;
      float rn0 = __builtin_amdgcn_rcpf(den.x);
      float rn1 = __builtin_amdgcn_rcpf(den.y);
      rn0 = rn0 * fmaf(-den.x, rn0, 2.0f);   // 1 Newton step each
      rn1 = rn1 * fmaf(-den.y, rn1, 2.0f);
      ssum = fmaf(num.x, rn0, ssum);
      ssum = fmaf(num.y, rn1, ssum);
    }
  }

  // ---- block partial + fused device-wide finale (tiny LDS, post-loop) ----
  __shared__ float  wred[4];
  __shared__ double dred[4];
  __shared__ int    flag;
#pragma unroll
  for (int off = 32; off > 0; off >>= 1) ssum += __shfl_xor(ssum, off, 64);
  const int wid = tid >> 6;
  if ((tid & 63) == 0) wred[wid] = ssum;
  __syncthreads();
  if (tid == 0) {
    const float bsum = wred[0] + wred[1] + wred[2] + wred[3];
    atomicExch(&partial[bat * NB + band], bsum);   // device-scope write
    __threadfence();
    const unsigned old = atomicAdd(counter, 1u);
    flag = (old == CBASE + (unsigned)NBLOCKS - 1u) ? 1 : 0;
  }
  __syncthreads();
  if (flag) {                       // block-uniform: last block reduces all
    double s = 0.0;
    for (int i = tid; i < NBLOCKS; i += TPB)
      s += (double)atomicAdd(&partial[i], 0.0f);   // coherent read via RMW
#pragma unroll
    for (int off = 32; off > 0; off >>= 1) s += __shfl_xor(s, off, 64);
    if ((tid & 63) == 0) dred[wid] = s;
    __syncthreads();
    if (tid == 0)
      out[0] = (float)((dred[0] + dred[1] + dred[2] + dred[3]) /
                       (double)((size_t)BATCH * HH * WW));
  }
}

extern "C" void kernel_launch(void* const* d_in, const int* in_sizes, int n_in,
                              void* d_out, int out_size, void* d_ws, size_t ws_size,
                              hipStream_t stream) {
  const float* img1 = (const float*)d_in[0];
  const float* img2 = (const float*)d_in[1];
  float* out = (float*)d_out;
  unsigned* counter = (unsigned*)d_ws;
  float* partial = (float*)((char*)d_ws + 16);
  dim3 grid(NB, BATCH);
  ssim_main<<<grid, TPB, 0, stream>>>(img1, img2, counter, partial, out);
}

// Round 4
// 130.947 us; speedup vs baseline: 1.8497x; 1.8497x over previous
//
#include <hip/hip_runtime.h>

#define HH 512
#define WW 512
#define BATCH 32
#define BH 16                 // output rows per block -> 8 pair-phases
#define NB (HH / BH)          // 32
#define TPB 256               // 4 waves; 2 cols/thread
#define NBLOCKS (NB * BATCH)  // 1024
#define PW 528                // padded f2 width per array: 9 left + 512 + 7 right
#define BUFF (5 * PW * 2)     // floats per buffer (21120 B)
#define CBASE 0xAAAAAAAAu     // harness poisons d_ws to 0xAA before every launch

// R15 = R11 chassis (proven 53-60us dispatch, 48 VGPR) + LDS DOUBLE-BUFFER =
// ONE barrier per phase (8/block vs 16). Evidence: R11 wall/CU-phase = 16.5k
// cy vs LDS 6.7k + VALU 2.8k; wall/16 wave-phases ~= 1030 cy = one wave's
// serial critical path -> near-zero inter-wave overlap from the 2-barrier
// lock-step convoy. R12 (more blocks, 2x worse) and R13 (intra-phase ILP,
// neutral) never reduced barrier count. R14 (no-LDS unrolled streaming) blew
// the I-cache (~50KB straight-line code) - not evidence against LDS.
// Delta from R11: phase q stores vert(q) -> buf[q&1], ONE __syncthreads,
// reads buf[q&1]. Phase q+1 writes the OTHER buffer, so read->write races
// are fenced by the single intervening barrier. Halos of both buffers zeroed
// once. LDS 42.2KB -> 3 blocks/CU (12 waves; R13 showed ~5 waves suffices).
// Predict: dur 55 -> 38-47us, VALUBusy 30 -> 38-45%, FETCH/conflicts/VGPR
// unchanged. Null (=55us): barrier count isn't the term -> attack LDS-read
// traffic next. Tripwires: WRITE_SIZE ~68KB (spill), VGPR <= 64.

typedef float f2 __attribute__((ext_vector_type(2)));

__global__ __launch_bounds__(TPB) void ssim_main(
    const float* __restrict__ img1,
    const float* __restrict__ img2,
    unsigned* __restrict__ counter,     // ws + 0   (starts at CBASE, poisoned)
    float* __restrict__ partial,        // ws + 16  (NBLOCKS floats)
    float* __restrict__ out)
{
  constexpr float G[11] = {
      0.00102838f, 0.00759876f, 0.03600077f, 0.10936070f, 0.21300553f,
      0.26601171f,
      0.21300553f, 0.10936070f, 0.03600077f, 0.00759876f, 0.00102838f};
  constexpr float C1 = 1.0e-4f;
  constexpr float C2 = 9.0e-4f;

  const int tid  = threadIdx.x;
  const int band = blockIdx.x;
  const int bat  = blockIdx.y;
  const int r0   = band * BH;
  const float* p1 = img1 + (size_t)bat * (HH * WW);
  const float* p2 = img2 + (size_t)bat * (HH * WW);
  const int c0 = tid * 2;

  // LDS: TWO buffers of 5 arrays x PW f2 (f2 = (row0,row1) of the pair).
  // Buffer b at sp + b*BUFF. f2 index for col c is c+9.
  __shared__ __align__(16) float sp[2 * BUFF];

  // Zero the halo f2s of BOTH buffers: idx 0..8 and 521..527 per array.
  // tid 0..159: a = buffer*5 + array (arrays of both buffers are contiguous).
  if (tid < 160) {
    const int a = tid >> 4, s = tid & 15;
    const int idx = (s < 9) ? s : (512 + s);
    *(f2*)(sp + a * (2 * PW) + 2 * idx) = f2{0.f, 0.f};
  }

  // Register sliding window: rows r0-5 .. r0+6, both images (48 VGPRs).
  float2 w1[12], w2[12];
#pragma unroll
  for (int j = 0; j < 12; ++j) {
    const int r = r0 - 5 + j;
    float2 a = make_float2(0.f, 0.f), b = a;
    if (r >= 0 && r < HH) {
      a = *(const float2*)(p1 + r * WW + c0);
      b = *(const float2*)(p2 + r * WW + c0);
    }
    w1[j] = a; w2[j] = b;
  }
  // NOTE: no barrier here — the first loop barrier fences halo zeros too.

  float ssum = 0.f;
  int sel = 0;

#pragma unroll 1
  for (int q = 0; q < BH; q += 2) {
    float* const spb = sp + sel * BUFF;   // this phase's buffer

    // Prefetch the two rows needed by the NEXT pair.
    float2 ta1 = make_float2(0.f, 0.f), ta2 = ta1, tb1 = ta1, tb2 = ta1;
    if (q + 2 < BH) {
      const int ra = r0 + 7 + q;
      const int rb = r0 + 8 + q;
      if (ra < HH) {
        ta1 = *(const float2*)(p1 + ra * WW + c0);
        ta2 = *(const float2*)(p2 + ra * WW + c0);
      }
      if (rb < HH) {
        tb1 = *(const float2*)(p1 + rb * WW + c0);
        tb2 = *(const float2*)(p2 + rb * WW + c0);
      }
    }

    // ---- vertical blur, ROW-PAIR PACKED: acc2[a][col] = (row0, row1) ----
    // row0 (r0+q):   tap e=0..10, weight G[e]
    // row1 (r0+q+1): tap e=1..11, weight G[e-1]
    f2 acc2[5][2];
#pragma unroll
    for (int a = 0; a < 5; ++a) { acc2[a][0] = f2{0.f, 0.f}; acc2[a][1] = f2{0.f, 0.f}; }

#pragma unroll
    for (int e = 0; e < 12; ++e) {
      const f2 g2 = f2{(e < 11) ? G[e] : 0.f, (e > 0) ? G[e - 1] : 0.f};
      const float xv[2] = {w1[e].x, w1[e].y};
      const float yv[2] = {w2[e].x, w2[e].y};
#pragma unroll
      for (int i = 0; i < 2; ++i) {
        const float x = xv[i], y = yv[i];
        const float xx = x * x, yy = y * y, xy = x * y;
        acc2[0][i] = __builtin_elementwise_fma(g2, f2{x,  x},  acc2[0][i]);
        acc2[1][i] = __builtin_elementwise_fma(g2, f2{y,  y},  acc2[1][i]);
        acc2[2][i] = __builtin_elementwise_fma(g2, f2{xx, xx}, acc2[2][i]);
        acc2[3][i] = __builtin_elementwise_fma(g2, f2{yy, yy}, acc2[3][i]);
        acc2[4][i] = __builtin_elementwise_fma(g2, f2{xy, xy}, acc2[4][i]);
      }
    }

#pragma unroll
    for (int a = 0; a < 5; ++a) {
      float* base = spb + a * (2 * PW) + 4 * tid + 18;  // f2 idx c0+9
      *(f2*)(base)     = acc2[a][0];
      *(f2*)(base + 2) = acc2[a][1];
    }

    __syncthreads();   // the ONLY barrier: this phase's stores visible.
                       // (Also fences prev phase's reads of the OTHER buffer
                       //  against its next overwrite, two phases away.)

    // ---- horizontal blur, packed: h2[a][j] = (row0, row1) of out col c0+j
    f2 h2[5][2];
#pragma unroll
    for (int a = 0; a < 5; ++a) {
      const float* base = spb + a * (2 * PW);
      // t2[i] = f2 for col c0-5+i  (f2 idx 2tid+4 .. 2tid+15, 6 aligned b128)
      f2 t2[12];
#pragma unroll
      for (int m = 0; m < 6; ++m) {
        const float4 X = *(const float4*)(base + 4 * tid + 8 + 4 * m);
        t2[2 * m]     = f2{X.x, X.y};
        t2[2 * m + 1] = f2{X.z, X.w};
      }
#pragma unroll
      for (int j = 0; j < 2; ++j) {
        f2 hv = f2{0.f, 0.f};
#pragma unroll
        for (int k = 0; k < 11; ++k)
          hv = __builtin_elementwise_fma(f2{G[k], G[k]}, t2[j + k], hv);
        h2[a][j] = hv;
      }
    }

#pragma unroll
    for (int j = 0; j < 2; ++j) {
      const f2 mu1 = h2[0][j], mu2 = h2[1][j];
      const f2 mu12 = mu1 * mu2;
      const f2 den1 = __builtin_elementwise_fma(
          mu1, mu1, __builtin_elementwise_fma(mu2, mu2, f2{C1, C1}));
      const f2 vs   = (h2[2][j] + h2[3][j]) - den1 + f2{C1 + C2, C1 + C2};
      const f2 sg12 = h2[4][j] - mu12;
      const f2 num = (mu12 + mu12 + f2{C1, C1}) * (sg12 + sg12 + f2{C2, C2});
      const f2 den = den1 * vs;
      float rn0 = __builtin_amdgcn_rcpf(den.x);
      float rn1 = __builtin_amdgcn_rcpf(den.y);
      rn0 = rn0 * fmaf(-den.x, rn0, 2.0f);   // 1 Newton step each
      rn1 = rn1 * fmaf(-den.y, rn1, 2.0f);
      ssum = fmaf(num.x, rn0, ssum);
      ssum = fmaf(num.y, rn1, ssum);
    }

    // NO second barrier: next phase writes the other buffer.

    // slide window down two rows
#pragma unroll
    for (int j = 0; j < 10; ++j) { w1[j] = w1[j + 2]; w2[j] = w2[j + 2]; }
    w1[10] = ta1; w2[10] = ta2;
    w1[11] = tb1; w2[11] = tb2;
    sel ^= 1;
  }

  // ---- block partial + fused device-wide finale ----
  // sp[0..16] lies in buf0's halo region; last phase (q=14) read buf1, and
  // any wave still in the loop is past the q=14 barrier -> no reader of buf0.
#pragma unroll
  for (int off = 32; off > 0; off >>= 1) ssum += __shfl_xor(ssum, off, 64);
  float*  wred = sp;
  double* dred = (double*)(sp + 8);
  int*    flag = (int*)(sp + 16);
  const int wid = tid >> 6;
  if ((tid & 63) == 0) wred[wid] = ssum;
  __syncthreads();
  if (tid == 0) {
    const float bsum = wred[0] + wred[1] + wred[2] + wred[3];
    atomicExch(&partial[bat * NB + band], bsum);   // device-scope write
    __threadfence();
    const unsigned old = atomicAdd(counter, 1u);
    flag[0] = (old == CBASE + (unsigned)NBLOCKS - 1u) ? 1 : 0;
  }
  __syncthreads();
  if (flag[0]) {                    // block-uniform: last block reduces all
    double s = 0.0;
    for (int i = tid; i < NBLOCKS; i += TPB)
      s += (double)atomicAdd(&partial[i], 0.0f);   // coherent read via RMW
#pragma unroll
    for (int off = 32; off > 0; off >>= 1) s += __shfl_xor(s, off, 64);
    if ((tid & 63) == 0) dred[wid] = s;
    __syncthreads();
    if (tid == 0)
      out[0] = (float)((dred[0] + dred[1] + dred[2] + dred[3]) /
                       (double)((size_t)BATCH * HH * WW));
  }
}

extern "C" void kernel_launch(void* const* d_in, const int* in_sizes, int n_in,
                              void* d_out, int out_size, void* d_ws, size_t ws_size,
                              hipStream_t stream) {
  const float* img1 = (const float*)d_in[0];
  const float* img2 = (const float*)d_in[1];
  float* out = (float*)d_out;
  unsigned* counter = (unsigned*)d_ws;
  float* partial = (float*)((char*)d_ws + 16);
  dim3 grid(NB, BATCH);
  ssim_main<<<grid, TPB, 0, stream>>>(img1, img2, counter, partial, out);
}

// Round 5
// 128.616 us; speedup vs baseline: 1.8833x; 1.0181x over previous
//
#include <hip/hip_runtime.h>

#define HH 512
#define WW 512
#define BATCH 32
#define BH 16                 // output rows per block -> 8 pair-phases
#define NB (HH / BH)          // 32
#define TPB 256               // 4 waves; 2 cols/thread
#define NBLOCKS (NB * BATCH)  // 1024 -> 4 blocks/CU
#define PW 528                // padded f2 width per array: 9 left + 512 + 7 right
#define CBASE 0xAAAAAAAAu     // harness poisons d_ws to 0xAA before every launch

// R16 = R11 chassis (proven best: 53-60us dispatch, 48 VGPR, single buffer,
// 2 barriers/phase) + ENTRY STAGGER. Evidence across R11-R15: VALU 0.30 +
// LDS ~0.38 (modeled) + HBM 0.11 ~= 0.79 of wall -> the three pipes run
// almost perfectly SERIALIZED CU-wide. Each SIMD holds 4 waves from 4
// DIFFERENT blocks; serialization requires all 4 blocks to sit in the same
// phase position = cross-block lock-step (identical code, simultaneous
// launch, shared-queue convoy attractor). All prior nulls (R12 blocks, R13
// ILP, R15 barrier count) never decorrelated blocks. Fix: s_sleep stagger
// ~0/1k/2k/3k cy by position in the co-resident quad {b,b+256,b+512,b+768}
// -> ((bid>>8)^bid)&3. One instruction; rest byte-identical to R11.
// Predict: dur 55 -> 42-48us, VALUBusy 30 -> 36-42%, all other counters
// unchanged. Null (<5%): lock-step theory dead -> instruction-cut program
// (slide-mov unroll, ~5-10%) then declare practical ceiling.

typedef float f2 __attribute__((ext_vector_type(2)));

__global__ __launch_bounds__(TPB) void ssim_main(
    const float* __restrict__ img1,
    const float* __restrict__ img2,
    unsigned* __restrict__ counter,     // ws + 0   (starts at CBASE, poisoned)
    float* __restrict__ partial,        // ws + 16  (NBLOCKS floats)
    float* __restrict__ out)
{
  constexpr float G[11] = {
      0.00102838f, 0.00759876f, 0.03600077f, 0.10936070f, 0.21300553f,
      0.26601171f,
      0.21300553f, 0.10936070f, 0.03600077f, 0.00759876f, 0.00102838f};
  constexpr float C1 = 1.0e-4f;
  constexpr float C2 = 9.0e-4f;

  const int tid  = threadIdx.x;
  const int band = blockIdx.x;
  const int bat  = blockIdx.y;
  const int bid  = band + NB * bat;

  // Desynchronize the co-resident quad: blocks {b, b+256, b+512, b+768}
  // share a CU. Sleep (quad-position)*1024 cycles so one block's LDS read
  // burst lands in the others' VALU windows. s_sleep(N) ~ N*64 cycles.
  {
    const int ph = ((bid >> 8) ^ bid) & 3;
    if (ph == 1) __builtin_amdgcn_s_sleep(16);
    else if (ph == 2) __builtin_amdgcn_s_sleep(32);
    else if (ph == 3) __builtin_amdgcn_s_sleep(48);
  }

  const int r0   = band * BH;
  const float* p1 = img1 + (size_t)bat * (HH * WW);
  const float* p2 = img2 + (size_t)bat * (HH * WW);
  const int c0 = tid * 2;

  // LDS: 5 arrays x PW f2 (each f2 = (row0,row1) of the pair) = 21120 B.
  // f2 index for col c is c+9; float offset = 2*(c+9).
  __shared__ __align__(16) float sp[5 * PW * 2];

  // Zero the halo f2s: idx 0..8 (cols -9..-1) and 521..527 (cols 512..518).
  if (tid < 80) {
    const int a = tid >> 4, s = tid & 15;
    const int idx = (s < 9) ? s : (512 + s);
    *(f2*)(sp + a * (2 * PW) + 2 * idx) = f2{0.f, 0.f};
  }

  // Register sliding window: rows r0-5 .. r0+6, both images (48 VGPRs).
  float2 w1[12], w2[12];
#pragma unroll
  for (int j = 0; j < 12; ++j) {
    const int r = r0 - 5 + j;
    float2 a = make_float2(0.f, 0.f), b = a;
    if (r >= 0 && r < HH) {
      a = *(const float2*)(p1 + r * WW + c0);
      b = *(const float2*)(p2 + r * WW + c0);
    }
    w1[j] = a; w2[j] = b;
  }

  __syncthreads();   // halo zeros visible

  float ssum = 0.f;

#pragma unroll 1
  for (int q = 0; q < BH; q += 2) {
    // Prefetch the two rows needed by the NEXT pair.
    float2 ta1 = make_float2(0.f, 0.f), ta2 = ta1, tb1 = ta1, tb2 = ta1;
    if (q + 2 < BH) {
      const int ra = r0 + 7 + q;
      const int rb = r0 + 8 + q;
      if (ra < HH) {
        ta1 = *(const float2*)(p1 + ra * WW + c0);
        ta2 = *(const float2*)(p2 + ra * WW + c0);
      }
      if (rb < HH) {
        tb1 = *(const float2*)(p1 + rb * WW + c0);
        tb2 = *(const float2*)(p2 + rb * WW + c0);
      }
    }

    // ---- vertical blur, ROW-PAIR PACKED: acc2[a][col] = (row0, row1) ----
    // row0 (r0+q):   tap e=0..10, weight G[e]
    // row1 (r0+q+1): tap e=1..11, weight G[e-1]
    f2 acc2[5][2];
#pragma unroll
    for (int a = 0; a < 5; ++a) { acc2[a][0] = f2{0.f, 0.f}; acc2[a][1] = f2{0.f, 0.f}; }

#pragma unroll
    for (int e = 0; e < 12; ++e) {
      const f2 g2 = f2{(e < 11) ? G[e] : 0.f, (e > 0) ? G[e - 1] : 0.f};
      const float xv[2] = {w1[e].x, w1[e].y};
      const float yv[2] = {w2[e].x, w2[e].y};
#pragma unroll
      for (int i = 0; i < 2; ++i) {
        const float x = xv[i], y = yv[i];
        const float xx = x * x, yy = y * y, xy = x * y;
        acc2[0][i] = __builtin_elementwise_fma(g2, f2{x,  x},  acc2[0][i]);
        acc2[1][i] = __builtin_elementwise_fma(g2, f2{y,  y},  acc2[1][i]);
        acc2[2][i] = __builtin_elementwise_fma(g2, f2{xx, xx}, acc2[2][i]);
        acc2[3][i] = __builtin_elementwise_fma(g2, f2{yy, yy}, acc2[3][i]);
        acc2[4][i] = __builtin_elementwise_fma(g2, f2{xy, xy}, acc2[4][i]);
      }
    }

#pragma unroll
    for (int a = 0; a < 5; ++a) {
      float* base = sp + a * (2 * PW) + 4 * tid + 18;  // f2 idx c0+9
      *(f2*)(base)     = acc2[a][0];
      *(f2*)(base + 2) = acc2[a][1];
    }

    __syncthreads();   // barrier 1: pair stores visible

    // ---- horizontal blur, packed: h2[a][j] = (row0, row1) of out col c0+j
    f2 h2[5][2];
#pragma unroll
    for (int a = 0; a < 5; ++a) {
      const float* base = sp + a * (2 * PW);
      // t2[i] = f2 for col c0-5+i  (f2 idx 2tid+4 .. 2tid+15, 6 aligned b128)
      f2 t2[12];
#pragma unroll
      for (int m = 0; m < 6; ++m) {
        const float4 X = *(const float4*)(base + 4 * tid + 8 + 4 * m);
        t2[2 * m]     = f2{X.x, X.y};
        t2[2 * m + 1] = f2{X.z, X.w};
      }
#pragma unroll
      for (int j = 0; j < 2; ++j) {
        f2 hv = f2{0.f, 0.f};
#pragma unroll
        for (int k = 0; k < 11; ++k)
          hv = __builtin_elementwise_fma(f2{G[k], G[k]}, t2[j + k], hv);
        h2[a][j] = hv;
      }
    }

#pragma unroll
    for (int j = 0; j < 2; ++j) {
      const f2 mu1 = h2[0][j], mu2 = h2[1][j];
      const f2 mu12 = mu1 * mu2;
      const f2 den1 = __builtin_elementwise_fma(
          mu1, mu1, __builtin_elementwise_fma(mu2, mu2, f2{C1, C1}));
      const f2 vs   = (h2[2][j] + h2[3][j]) - den1 + f2{C1 + C2, C1 + C2};
      const f2 sg12 = h2[4][j] - mu12;
      const f2 num = (mu12 + mu12 + f2{C1, C1}) * (sg12 + sg12 + f2{C2, C2});
      const f2 den = den1 * vs;
      float rn0 = __builtin_amdgcn_rcpf(den.x);
      float rn1 = __builtin_amdgcn_rcpf(den.y);
      rn0 = rn0 * fmaf(-den.x, rn0, 2.0f);   // 1 Newton step each
      rn1 = rn1 * fmaf(-den.y, rn1, 2.0f);
      ssum = fmaf(num.x, rn0, ssum);
      ssum = fmaf(num.y, rn1, ssum);
    }

    __syncthreads();   // barrier 2: reads done before next pair's stores

    // slide window down two rows
#pragma unroll
    for (int j = 0; j < 10; ++j) { w1[j] = w1[j + 2]; w2[j] = w2[j + 2]; }
    w1[10] = ta1; w2[10] = ta2;
    w1[11] = tb1; w2[11] = tb2;
  }

  // ---- block partial + fused device-wide finale (LDS reused post-loop) ----
#pragma unroll
  for (int off = 32; off > 0; off >>= 1) ssum += __shfl_xor(ssum, off, 64);
  float*  wred = sp;                 // halo region, dead after last barrier
  double* dred = (double*)(sp + 8);
  int*    flag = (int*)(sp + 16);
  const int wid = tid >> 6;
  if ((tid & 63) == 0) wred[wid] = ssum;
  __syncthreads();
  if (tid == 0) {
    const float bsum = wred[0] + wred[1] + wred[2] + wred[3];
    atomicExch(&partial[bat * NB + band], bsum);   // device-scope write
    __threadfence();
    const unsigned old = atomicAdd(counter, 1u);
    flag[0] = (old == CBASE + (unsigned)NBLOCKS - 1u) ? 1 : 0;
  }
  __syncthreads();
  if (flag[0]) {                    // block-uniform: last block reduces all
    double s = 0.0;
    for (int i = tid; i < NBLOCKS; i += TPB)
      s += (double)atomicAdd(&partial[i], 0.0f);   // coherent read via RMW
#pragma unroll
    for (int off = 32; off > 0; off >>= 1) s += __shfl_xor(s, off, 64);
    if ((tid & 63) == 0) dred[wid] = s;
    __syncthreads();
    if (tid == 0)
      out[0] = (float)((dred[0] + dred[1] + dred[2] + dred[3]) /
                       (double)((size_t)BATCH * HH * WW));
  }
}

extern "C" void kernel_launch(void* const* d_in, const int* in_sizes, int n_in,
                              void* d_out, int out_size, void* d_ws, size_t ws_size,
                              hipStream_t stream) {
  const float* img1 = (const float*)d_in[0];
  const float* img2 = (const float*)d_in[1];
  float* out = (float*)d_out;
  unsigned* counter = (unsigned*)d_ws;
  float* partial = (float*)((char*)d_ws + 16);
  dim3 grid(NB, BATCH);
  ssim_main<<<grid, TPB, 0, stream>>>(img1, img2, counter, partial, out);
}

// Round 6
// 124.902 us; speedup vs baseline: 1.9393x; 1.0297x over previous
//
#include <hip/hip_runtime.h>

#define HH 512
#define WW 512
#define BATCH 32
#define BH 16                 // output rows per block -> 8 pair-phases
#define NB (HH / BH)          // 32
#define TPB 256               // 4 waves; 2 cols/thread
#define NBLOCKS (NB * BATCH)  // 1024 -> 4 blocks/CU
#define PW 528                // padded f2 width per array: 9 left + 512 + 7 right
#define CBASE 0xAAAAAAAAu     // harness poisons d_ws to 0xAA before every launch

// R17 = R11 chassis (proven best: 53-60us; R12/R13/R15/R16 structural probes
// all null/worse) + ALGEBRAIC 5->4 ARRAY FUSION. SSIM only ever uses
// blur(x^2)+blur(y^2) as a SUM (vs-term); blur is linear -> convolve
// s = x^2+y^2 as ONE array: {x, y, s, xy}. Cuts LDS ops/phase 40->32 (-20%),
// horiz FMA -20%, vert ops -12%, LDS 21.1->16.9KB, and shortens the per-wave
// serial phase path (the surviving wall candidate: ~1030cy x 8 phases).
// Predict: dur 55 -> 46-50us; SQ_LDS_BANK_CONFLICT 1310720 -> 1048576
// (exactly 32/40, proves the cut landed); FETCH/WRITE/VGPR unchanged.
// Null (conflicts drop, dur >= 53us): instruction count also not the wall ->
// barrier+latency floor; declare structure at practical ceiling.

typedef float f2 __attribute__((ext_vector_type(2)));

__global__ __launch_bounds__(TPB) void ssim_main(
    const float* __restrict__ img1,
    const float* __restrict__ img2,
    unsigned* __restrict__ counter,     // ws + 0   (starts at CBASE, poisoned)
    float* __restrict__ partial,        // ws + 16  (NBLOCKS floats)
    float* __restrict__ out)
{
  constexpr float G[11] = {
      0.00102838f, 0.00759876f, 0.03600077f, 0.10936070f, 0.21300553f,
      0.26601171f,
      0.21300553f, 0.10936070f, 0.03600077f, 0.00759876f, 0.00102838f};
  constexpr float C1 = 1.0e-4f;
  constexpr float C2 = 9.0e-4f;

  const int tid  = threadIdx.x;
  const int band = blockIdx.x;
  const int bat  = blockIdx.y;
  const int r0   = band * BH;
  const float* p1 = img1 + (size_t)bat * (HH * WW);
  const float* p2 = img2 + (size_t)bat * (HH * WW);
  const int c0 = tid * 2;

  // LDS: 4 arrays x PW f2 (each f2 = (row0,row1) of the pair) = 16896 B.
  // a=0: x, a=1: y, a=2: s=x^2+y^2, a=3: p=x*y.
  // f2 index for col c is c+9; float offset = 2*(c+9).
  __shared__ __align__(16) float sp[4 * PW * 2];

  // Zero the halo f2s: idx 0..8 (cols -9..-1) and 521..527 (cols 512..518).
  if (tid < 64) {
    const int a = tid >> 4, s = tid & 15;
    const int idx = (s < 9) ? s : (512 + s);
    *(f2*)(sp + a * (2 * PW) + 2 * idx) = f2{0.f, 0.f};
  }

  // Register sliding window: rows r0-5 .. r0+6, both images (48 VGPRs).
  float2 w1[12], w2[12];
#pragma unroll
  for (int j = 0; j < 12; ++j) {
    const int r = r0 - 5 + j;
    float2 a = make_float2(0.f, 0.f), b = a;
    if (r >= 0 && r < HH) {
      a = *(const float2*)(p1 + r * WW + c0);
      b = *(const float2*)(p2 + r * WW + c0);
    }
    w1[j] = a; w2[j] = b;
  }

  __syncthreads();   // halo zeros visible

  float ssum = 0.f;

#pragma unroll 1
  for (int q = 0; q < BH; q += 2) {
    // Prefetch the two rows needed by the NEXT pair.
    float2 ta1 = make_float2(0.f, 0.f), ta2 = ta1, tb1 = ta1, tb2 = ta1;
    if (q + 2 < BH) {
      const int ra = r0 + 7 + q;
      const int rb = r0 + 8 + q;
      if (ra < HH) {
        ta1 = *(const float2*)(p1 + ra * WW + c0);
        ta2 = *(const float2*)(p2 + ra * WW + c0);
      }
      if (rb < HH) {
        tb1 = *(const float2*)(p1 + rb * WW + c0);
        tb2 = *(const float2*)(p2 + rb * WW + c0);
      }
    }

    // ---- vertical blur, ROW-PAIR PACKED: acc2[a][col] = (row0, row1) ----
    // row0 (r0+q):   tap e=0..10, weight G[e]
    // row1 (r0+q+1): tap e=1..11, weight G[e-1]
    f2 acc2[4][2];
#pragma unroll
    for (int a = 0; a < 4; ++a) { acc2[a][0] = f2{0.f, 0.f}; acc2[a][1] = f2{0.f, 0.f}; }

#pragma unroll
    for (int e = 0; e < 12; ++e) {
      const f2 g2 = f2{(e < 11) ? G[e] : 0.f, (e > 0) ? G[e - 1] : 0.f};
      const float xv[2] = {w1[e].x, w1[e].y};
      const float yv[2] = {w2[e].x, w2[e].y};
#pragma unroll
      for (int i = 0; i < 2; ++i) {
        const float x = xv[i], y = yv[i];
        const float s = fmaf(y, y, x * x);   // x^2 + y^2 fused
        const float p = x * y;
        acc2[0][i] = __builtin_elementwise_fma(g2, f2{x, x}, acc2[0][i]);
        acc2[1][i] = __builtin_elementwise_fma(g2, f2{y, y}, acc2[1][i]);
        acc2[2][i] = __builtin_elementwise_fma(g2, f2{s, s}, acc2[2][i]);
        acc2[3][i] = __builtin_elementwise_fma(g2, f2{p, p}, acc2[3][i]);
      }
    }

#pragma unroll
    for (int a = 0; a < 4; ++a) {
      float* base = sp + a * (2 * PW) + 4 * tid + 18;  // f2 idx c0+9
      *(f2*)(base)     = acc2[a][0];
      *(f2*)(base + 2) = acc2[a][1];
    }

    __syncthreads();   // barrier 1: pair stores visible

    // ---- horizontal blur, packed: h2[a][j] = (row0, row1) of out col c0+j
    f2 h2[4][2];
#pragma unroll
    for (int a = 0; a < 4; ++a) {
      const float* base = sp + a * (2 * PW);
      // t2[i] = f2 for col c0-5+i  (f2 idx 2tid+4 .. 2tid+15, 6 aligned b128)
      f2 t2[12];
#pragma unroll
      for (int m = 0; m < 6; ++m) {
        const float4 X = *(const float4*)(base + 4 * tid + 8 + 4 * m);
        t2[2 * m]     = f2{X.x, X.y};
        t2[2 * m + 1] = f2{X.z, X.w};
      }
#pragma unroll
      for (int j = 0; j < 2; ++j) {
        f2 hv = f2{0.f, 0.f};
#pragma unroll
        for (int k = 0; k < 11; ++k)
          hv = __builtin_elementwise_fma(f2{G[k], G[k]}, t2[j + k], hv);
        h2[a][j] = hv;
      }
    }

#pragma unroll
    for (int j = 0; j < 2; ++j) {
      const f2 mu1 = h2[0][j], mu2 = h2[1][j];
      const f2 S   = h2[2][j], P   = h2[3][j];
      const f2 mu12 = mu1 * mu2;
      const f2 den1 = __builtin_elementwise_fma(
          mu1, mu1, __builtin_elementwise_fma(mu2, mu2, f2{C1, C1}));
      const f2 vs   = S - den1 + f2{C1 + C2, C1 + C2};
      const f2 sg12 = P - mu12;
      const f2 num = (mu12 + mu12 + f2{C1, C1}) * (sg12 + sg12 + f2{C2, C2});
      const f2 den = den1 * vs;
      float rn0 = __builtin_amdgcn_rcpf(den.x);
      float rn1 = __builtin_amdgcn_rcpf(den.y);
      rn0 = rn0 * fmaf(-den.x, rn0, 2.0f);   // 1 Newton step each
      rn1 = rn1 * fmaf(-den.y, rn1, 2.0f);
      ssum = fmaf(num.x, rn0, ssum);
      ssum = fmaf(num.y, rn1, ssum);
    }

    __syncthreads();   // barrier 2: reads done before next pair's stores

    // slide window down two rows
#pragma unroll
    for (int j = 0; j < 10; ++j) { w1[j] = w1[j + 2]; w2[j] = w2[j + 2]; }
    w1[10] = ta1; w2[10] = ta2;
    w1[11] = tb1; w2[11] = tb2;
  }

  // ---- block partial + fused device-wide finale (LDS reused post-loop) ----
#pragma unroll
  for (int off = 32; off > 0; off >>= 1) ssum += __shfl_xor(ssum, off, 64);
  float*  wred = sp;                 // halo region, dead after last barrier
  double* dred = (double*)(sp + 8);
  int*    flag = (int*)(sp + 16);
  const int wid = tid >> 6;
  if ((tid & 63) == 0) wred[wid] = ssum;
  __syncthreads();
  if (tid == 0) {
    const float bsum = wred[0] + wred[1] + wred[2] + wred[3];
    atomicExch(&partial[bat * NB + band], bsum);   // device-scope write
    __threadfence();
    const unsigned old = atomicAdd(counter, 1u);
    flag[0] = (old == CBASE + (unsigned)NBLOCKS - 1u) ? 1 : 0;
  }
  __syncthreads();
  if (flag[0]) {                    // block-uniform: last block reduces all
    double s = 0.0;
    for (int i = tid; i < NBLOCKS; i += TPB)
      s += (double)atomicAdd(&partial[i], 0.0f);   // coherent read via RMW
#pragma unroll
    for (int off = 32; off > 0; off >>= 1) s += __shfl_xor(s, off, 64);
    if ((tid & 63) == 0) dred[wid] = s;
    __syncthreads();
    if (tid == 0)
      out[0] = (float)((dred[0] + dred[1] + dred[2] + dred[3]) /
                       (double)((size_t)BATCH * HH * WW));
  }
}

extern "C" void kernel_launch(void* const* d_in, const int* in_sizes, int n_in,
                              void* d_out, int out_size, void* d_ws, size_t ws_size,
                              hipStream_t stream) {
  const float* img1 = (const float*)d_in[0];
  const float* img2 = (const float*)d_in[1];
  float* out = (float*)d_out;
  unsigned* counter = (unsigned*)d_ws;
  float* partial = (float*)((char*)d_ws + 16);
  dim3 grid(NB, BATCH);
  ssim_main<<<grid, TPB, 0, stream>>>(img1, img2, counter, partial, out);
}